// Round 1
// baseline (557.347 us; speedup 1.0000x reference)
//
#include <hip/hip_runtime.h>
#include <math.h>

#define NEG_INF (-INFINITY)

// encode_input_log: x[0]=-inf, x[1]=0, x[2+2i]=w[i], x[3+2i]=log1mexp(w[i])
__global__ void encode_kernel(const float* __restrict__ w, float* __restrict__ x, int n_vars) {
    int i = blockIdx.x * blockDim.x + threadIdx.x;
    if (i < n_vars) {
        float p = w[i];
        // log1mexp: log(1 - exp(p)), p < 0
        float neg = (p > -0.69314718055994531f) ? logf(-expm1f(p)) : log1pf(-expf(p));
        // coalesced 8B store of the interleaved pair
        reinterpret_cast<float2*>(x + 2)[i] = make_float2(p, neg);
    }
    if (i == 0) { x[0] = NEG_INF; x[1] = 0.0f; }
}

// product node (log semiring): y[i] = sum of 4 gathered log-values
__global__ void sum4_kernel(const float* __restrict__ x, const int* __restrict__ ptrs,
                            float* __restrict__ y, int n) {
    int i = blockIdx.x * blockDim.x + threadIdx.x;
    if (i < n) {
        int4 p = reinterpret_cast<const int4*>(ptrs)[i];
        // only -inf can appear (no +inf), so no nan from the adds
        y[i] = x[p.x] + x[p.y] + x[p.z] + x[p.w];
    }
}

// sum node (log semiring): numerically stable 4-way log-sum-exp
__global__ void logsum4_kernel(const float* __restrict__ x, const int* __restrict__ ptrs,
                               float* __restrict__ y, int n) {
    int i = blockIdx.x * blockDim.x + threadIdx.x;
    if (i < n) {
        int4 p = reinterpret_cast<const int4*>(ptrs)[i];
        float a = x[p.x], b = x[p.y], c = x[p.z], d = x[p.w];
        float m = fmaxf(fmaxf(a, b), fmaxf(c, d));
        float out;
        if (m == NEG_INF) {
            // all four -inf: ref = log(4+eps) + (-inf) = -inf
            out = NEG_INF;
        } else {
            // g - m <= 0; g = -inf gives exp(-inf) = 0 (matches nan_to_num path)
            float s = expf(a - m) + expf(b - m) + expf(c - m) + expf(d - m) + 1e-15f;
            out = logf(s) + m;
        }
        y[i] = out;
    }
}

extern "C" void kernel_launch(void* const* d_in, const int* in_sizes, int n_in,
                              void* d_out, int out_size, void* d_ws, size_t ws_size,
                              hipStream_t stream) {
    // d_in dict order: weights, ptrs0, csr0, n0, ptrs1, csr1, n1, ptrs2, csr2, n2, ptrs3, csr3, n3
    const float* w     = (const float*)d_in[0];
    const int*   ptrs0 = (const int*)d_in[1];
    const int*   ptrs1 = (const int*)d_in[4];
    const int*   ptrs2 = (const int*)d_in[7];
    const int*   ptrs3 = (const int*)d_in[10];

    const int n_vars = in_sizes[0];
    const int n0 = in_sizes[1] / 4;
    const int n1 = in_sizes[4] / 4;
    const int n2 = in_sizes[7] / 4;
    const int n3 = in_sizes[10] / 4;

    // workspace layout (256B-aligned chunks)
    char* ws = (char*)d_ws;
    size_t off = 0;
    float* x  = (float*)(ws + off); off += (((size_t)(2 + 2 * (size_t)n_vars)) * 4 + 255) & ~(size_t)255;
    float* y0 = (float*)(ws + off); off += ((size_t)n0 * 4 + 255) & ~(size_t)255;
    float* y1 = (float*)(ws + off); off += ((size_t)n1 * 4 + 255) & ~(size_t)255;
    float* y2 = (float*)(ws + off);
    float* out = (float*)d_out;

    const int B = 256;
    encode_kernel<<<(n_vars + B - 1) / B, B, 0, stream>>>(w, x, n_vars);
    sum4_kernel   <<<(n0 + B - 1) / B, B, 0, stream>>>(x,  ptrs0, y0, n0);
    logsum4_kernel<<<(n1 + B - 1) / B, B, 0, stream>>>(y0, ptrs1, y1, n1);
    sum4_kernel   <<<(n2 + B - 1) / B, B, 0, stream>>>(y1, ptrs2, y2, n2);
    logsum4_kernel<<<(n3 + B - 1) / B, B, 0, stream>>>(y2, ptrs3, out, n3);
}

// Round 3
// 481.850 us; speedup vs baseline: 1.1567x; 1.1567x over previous
//
#include <hip/hip_runtime.h>
#include <math.h>

#define NEG_INF (-INFINITY)

typedef int v4i __attribute__((ext_vector_type(4)));

// Decode one encoded-x entry directly from w:
//   p==0 -> -inf ; p==1 -> 0 ; even p>=2 -> w[(p>>1)-1] ; odd p>=3 -> log1mexp(w[(p>>1)-1])
__device__ __forceinline__ float decode_w(const float* __restrict__ w, int p) {
    int j = (p >> 1) - 1;
    float v = w[j < 0 ? 0 : j];              // clamped: avoids OOB for p<2 lanes
    if (p & 1) v = (v > -0.69314718055994531f) ? logf(-expm1f(v)) : log1pf(-expf(v));
    if (p < 2) v = (p == 0) ? NEG_INF : 0.0f;
    return v;
}

// Layer 0 fused with encode: y[i] = sum of 4 decoded gathers from w (8 MB footprint).
__global__ __launch_bounds__(256) void sum4_enc_kernel(const float* __restrict__ w,
                                                       const v4i* __restrict__ ptrs,
                                                       float* __restrict__ y, int n, int h) {
    int t = blockIdx.x * blockDim.x + threadIdx.x;
    if (t >= h) return;
    v4i pA = __builtin_nontemporal_load(ptrs + t);
    int iB = t + h;
    bool hasB = iB < n;
    v4i pB = hasB ? __builtin_nontemporal_load(ptrs + iB) : pA;
    float a0 = decode_w(w, pA.x), a1 = decode_w(w, pA.y);
    float a2 = decode_w(w, pA.z), a3 = decode_w(w, pA.w);
    float b0 = decode_w(w, pB.x), b1 = decode_w(w, pB.y);
    float b2 = decode_w(w, pB.z), b3 = decode_w(w, pB.w);
    y[t] = (a0 + a1) + (a2 + a3);
    if (hasB) y[iB] = (b0 + b1) + (b2 + b3);
}

// product node (log semiring): y[i] = sum of 4 gathered log-values
__global__ __launch_bounds__(256) void sum4_kernel(const float* __restrict__ x,
                                                   const v4i* __restrict__ ptrs,
                                                   float* __restrict__ y, int n, int h) {
    int t = blockIdx.x * blockDim.x + threadIdx.x;
    if (t >= h) return;
    v4i pA = __builtin_nontemporal_load(ptrs + t);
    int iB = t + h;
    bool hasB = iB < n;
    v4i pB = hasB ? __builtin_nontemporal_load(ptrs + iB) : pA;
    float a0 = x[pA.x], a1 = x[pA.y], a2 = x[pA.z], a3 = x[pA.w];
    float b0 = x[pB.x], b1 = x[pB.y], b2 = x[pB.z], b3 = x[pB.w];
    y[t] = (a0 + a1) + (a2 + a3);
    if (hasB) y[iB] = (b0 + b1) + (b2 + b3);
}

// sum node (log semiring): numerically stable 4-way log-sum-exp
__device__ __forceinline__ float lse4(float a, float b, float c, float d) {
    float m = fmaxf(fmaxf(a, b), fmaxf(c, d));
    if (m == NEG_INF) return NEG_INF;        // all -inf: ref gives -inf
    float s = expf(a - m) + expf(b - m) + expf(c - m) + expf(d - m) + 1e-15f;
    return logf(s) + m;
}

__global__ __launch_bounds__(256) void logsum4_kernel(const float* __restrict__ x,
                                                      const v4i* __restrict__ ptrs,
                                                      float* __restrict__ y, int n, int h) {
    int t = blockIdx.x * blockDim.x + threadIdx.x;
    if (t >= h) return;
    v4i pA = __builtin_nontemporal_load(ptrs + t);
    int iB = t + h;
    bool hasB = iB < n;
    v4i pB = hasB ? __builtin_nontemporal_load(ptrs + iB) : pA;
    float a0 = x[pA.x], a1 = x[pA.y], a2 = x[pA.z], a3 = x[pA.w];
    float b0 = x[pB.x], b1 = x[pB.y], b2 = x[pB.z], b3 = x[pB.w];
    y[t] = lse4(a0, a1, a2, a3);
    if (hasB) y[iB] = lse4(b0, b1, b2, b3);
}

extern "C" void kernel_launch(void* const* d_in, const int* in_sizes, int n_in,
                              void* d_out, int out_size, void* d_ws, size_t ws_size,
                              hipStream_t stream) {
    // d_in dict order: weights, ptrs0, csr0, n0, ptrs1, csr1, n1, ptrs2, csr2, n2, ptrs3, csr3, n3
    const float* w     = (const float*)d_in[0];
    const v4i*   ptrs0 = (const v4i*)d_in[1];
    const v4i*   ptrs1 = (const v4i*)d_in[4];
    const v4i*   ptrs2 = (const v4i*)d_in[7];
    const v4i*   ptrs3 = (const v4i*)d_in[10];

    const int n0 = in_sizes[1] / 4;
    const int n1 = in_sizes[4] / 4;
    const int n2 = in_sizes[7] / 4;
    const int n3 = in_sizes[10] / 4;

    // workspace layout (256B-aligned chunks)
    char* ws = (char*)d_ws;
    size_t off = 0;
    float* y0 = (float*)(ws + off); off += ((size_t)n0 * 4 + 255) & ~(size_t)255;
    float* y1 = (float*)(ws + off); off += ((size_t)n1 * 4 + 255) & ~(size_t)255;
    float* y2 = (float*)(ws + off);
    float* out = (float*)d_out;

    const int B = 256;
    int h0 = (n0 + 1) / 2, h1 = (n1 + 1) / 2, h2 = (n2 + 1) / 2, h3 = (n3 + 1) / 2;
    sum4_enc_kernel<<<(h0 + B - 1) / B, B, 0, stream>>>(w,  ptrs0, y0, n0, h0);
    logsum4_kernel <<<(h1 + B - 1) / B, B, 0, stream>>>(y0, ptrs1, y1, n1, h1);
    sum4_kernel    <<<(h2 + B - 1) / B, B, 0, stream>>>(y1, ptrs2, y2, n2, h2);
    logsum4_kernel <<<(h3 + B - 1) / B, B, 0, stream>>>(y2, ptrs3, out, n3, h3);
}

// Round 4
// 376.297 us; speedup vs baseline: 1.4811x; 1.2805x over previous
//
#include <hip/hip_runtime.h>
#include <math.h>

#define NEG_INF (-INFINITY)

typedef int      v4i __attribute__((ext_vector_type(4)));
typedef float    v4f __attribute__((ext_vector_type(4)));
typedef _Float16 v4h __attribute__((ext_vector_type(4)));

// fast log1mexp for v < 0: log(1 - e^v). Rel err ~1e-6, ~10 VALU ops.
__device__ __forceinline__ float fast_log1mexp(float v) {
    if (v > -0.125f) {
        // 4-term Taylor for expm1(v): rel err < 3e-6 on (-0.125, 0)
        float e = v * (1.0f + v * (0.5f + v * (0.16666667f + v * 0.041666667f)));
        return __logf(-e);
    }
    return __logf(1.0f - __expf(v));   // 1 - e^v >= 0.117, no cancellation
}

// w (fp32) -> wh (fp16), vectorized 4/thread with scalar tail
__global__ __launch_bounds__(256) void cvt_kernel(const float* __restrict__ w,
                                                  _Float16* __restrict__ wh, int n) {
    int i = blockIdx.x * blockDim.x + threadIdx.x;
    int n4 = n >> 2;
    if (i < n4) {
        v4f v = reinterpret_cast<const v4f*>(w)[i];
        v4h o;
        o.x = (_Float16)v.x; o.y = (_Float16)v.y;
        o.z = (_Float16)v.z; o.w = (_Float16)v.w;
        reinterpret_cast<v4h*>(wh)[i] = o;
    }
    int base = n4 << 2;
    if (i < (n - base)) wh[base + i] = (_Float16)w[base + i];
}

// Decode encoded-x entry p from the fp16 weight table (4 MB, L2-resident):
//   p==0 -> -inf ; p==1 -> 0 ; even p>=2 -> w[(p>>1)-1] ; odd -> log1mexp(w[..])
__device__ __forceinline__ float decode_h(const _Float16* __restrict__ wh, int p) {
    int j = (p >> 1) - 1;
    float v = (float)wh[j < 0 ? 0 : j];     // clamp avoids OOB for p<2
    float r = (p & 1) ? fast_log1mexp(v) : v;
    if (p < 2) r = (p == 0) ? NEG_INF : 0.0f;
    return r;
}

// Layer 0: product node fused with encode; gathers fp16 w, writes fp16 y0.
__global__ __launch_bounds__(256) void sum4_enc_kernel(const _Float16* __restrict__ wh,
                                                       const v4i* __restrict__ ptrs,
                                                       _Float16* __restrict__ y, int n, int h) {
    int t = blockIdx.x * blockDim.x + threadIdx.x;
    if (t >= h) return;
    v4i pA = __builtin_nontemporal_load(ptrs + t);
    int iB = t + h;
    bool hasB = iB < n;
    v4i pB = hasB ? __builtin_nontemporal_load(ptrs + iB) : pA;
    float a = (decode_h(wh, pA.x) + decode_h(wh, pA.y)) + (decode_h(wh, pA.z) + decode_h(wh, pA.w));
    float b = (decode_h(wh, pB.x) + decode_h(wh, pB.y)) + (decode_h(wh, pB.z) + decode_h(wh, pB.w));
    __builtin_nontemporal_store((_Float16)a, y + t);
    if (hasB) __builtin_nontemporal_store((_Float16)b, y + iB);
}

// Product node: fp16 gather -> fp16 out
__global__ __launch_bounds__(256) void sum4_h2h_kernel(const _Float16* __restrict__ x,
                                                       const v4i* __restrict__ ptrs,
                                                       _Float16* __restrict__ y, int n, int h) {
    int t = blockIdx.x * blockDim.x + threadIdx.x;
    if (t >= h) return;
    v4i pA = __builtin_nontemporal_load(ptrs + t);
    int iB = t + h;
    bool hasB = iB < n;
    v4i pB = hasB ? __builtin_nontemporal_load(ptrs + iB) : pA;
    float a = ((float)x[pA.x] + (float)x[pA.y]) + ((float)x[pA.z] + (float)x[pA.w]);
    float b = ((float)x[pB.x] + (float)x[pB.y]) + ((float)x[pB.z] + (float)x[pB.w]);
    __builtin_nontemporal_store((_Float16)a, y + t);
    if (hasB) __builtin_nontemporal_store((_Float16)b, y + iB);
}

// 4-way log-sum-exp, numerically stable, cheap transcendentals
__device__ __forceinline__ float lse4(float a, float b, float c, float d) {
    float m = fmaxf(fmaxf(a, b), fmaxf(c, d));
    if (m == NEG_INF) return NEG_INF;       // all four -inf: ref yields -inf
    float s = __expf(a - m) + __expf(b - m) + __expf(c - m) + __expf(d - m) + 1e-15f;
    return __logf(s) + m;
}

// Sum node: fp16 gather -> fp16 out (layer 1)
__global__ __launch_bounds__(256) void logsum4_h2h_kernel(const _Float16* __restrict__ x,
                                                          const v4i* __restrict__ ptrs,
                                                          _Float16* __restrict__ y, int n, int h) {
    int t = blockIdx.x * blockDim.x + threadIdx.x;
    if (t >= h) return;
    v4i pA = __builtin_nontemporal_load(ptrs + t);
    int iB = t + h;
    bool hasB = iB < n;
    v4i pB = hasB ? __builtin_nontemporal_load(ptrs + iB) : pA;
    float a = lse4((float)x[pA.x], (float)x[pA.y], (float)x[pA.z], (float)x[pA.w]);
    float b = lse4((float)x[pB.x], (float)x[pB.y], (float)x[pB.z], (float)x[pB.w]);
    __builtin_nontemporal_store((_Float16)a, y + t);
    if (hasB) __builtin_nontemporal_store((_Float16)b, y + iB);
}

// Sum node: fp16 gather -> fp32 out (final layer)
__global__ __launch_bounds__(256) void logsum4_h2f_kernel(const _Float16* __restrict__ x,
                                                          const v4i* __restrict__ ptrs,
                                                          float* __restrict__ y, int n, int h) {
    int t = blockIdx.x * blockDim.x + threadIdx.x;
    if (t >= h) return;
    v4i pA = __builtin_nontemporal_load(ptrs + t);
    int iB = t + h;
    bool hasB = iB < n;
    v4i pB = hasB ? __builtin_nontemporal_load(ptrs + iB) : pA;
    float a = lse4((float)x[pA.x], (float)x[pA.y], (float)x[pA.z], (float)x[pA.w]);
    float b = lse4((float)x[pB.x], (float)x[pB.y], (float)x[pB.z], (float)x[pB.w]);
    __builtin_nontemporal_store(a, y + t);
    if (hasB) __builtin_nontemporal_store(b, y + iB);
}

extern "C" void kernel_launch(void* const* d_in, const int* in_sizes, int n_in,
                              void* d_out, int out_size, void* d_ws, size_t ws_size,
                              hipStream_t stream) {
    // d_in dict order: weights, ptrs0, csr0, n0, ptrs1, csr1, n1, ptrs2, csr2, n2, ptrs3, csr3, n3
    const float* w     = (const float*)d_in[0];
    const v4i*   ptrs0 = (const v4i*)d_in[1];
    const v4i*   ptrs1 = (const v4i*)d_in[4];
    const v4i*   ptrs2 = (const v4i*)d_in[7];
    const v4i*   ptrs3 = (const v4i*)d_in[10];

    const int n_vars = in_sizes[0];
    const int n0 = in_sizes[1] / 4;
    const int n1 = in_sizes[4] / 4;
    const int n2 = in_sizes[7] / 4;
    const int n3 = in_sizes[10] / 4;

    // workspace layout (256B-aligned chunks), all fp16
    char* ws = (char*)d_ws;
    size_t off = 0;
    _Float16* wh = (_Float16*)(ws + off); off += ((size_t)n_vars * 2 + 255) & ~(size_t)255;
    _Float16* y0 = (_Float16*)(ws + off); off += ((size_t)n0 * 2 + 255) & ~(size_t)255;
    _Float16* y1 = (_Float16*)(ws + off); off += ((size_t)n1 * 2 + 255) & ~(size_t)255;
    _Float16* y2 = (_Float16*)(ws + off);
    float* out = (float*)d_out;

    const int B = 256;
    int hc = (n_vars + 3) / 4;              // cvt threads (4 elems each)
    int h0 = (n0 + 1) / 2, h1 = (n1 + 1) / 2, h2 = (n2 + 1) / 2, h3 = (n3 + 1) / 2;
    cvt_kernel        <<<(hc + B - 1) / B, B, 0, stream>>>(w, wh, n_vars);
    sum4_enc_kernel   <<<(h0 + B - 1) / B, B, 0, stream>>>(wh, ptrs0, y0, n0, h0);
    logsum4_h2h_kernel<<<(h1 + B - 1) / B, B, 0, stream>>>(y0, ptrs1, y1, n1, h1);
    sum4_h2h_kernel   <<<(h2 + B - 1) / B, B, 0, stream>>>(y1, ptrs2, y2, n2, h2);
    logsum4_h2f_kernel<<<(h3 + B - 1) / B, B, 0, stream>>>(y2, ptrs3, out, n3, h3);
}

// Round 5
// 372.133 us; speedup vs baseline: 1.4977x; 1.0112x over previous
//
#include <hip/hip_runtime.h>
#include <math.h>

#define NEG_INF (-INFINITY)

typedef int      v4i __attribute__((ext_vector_type(4)));
typedef float    v4f __attribute__((ext_vector_type(4)));
typedef _Float16 v4h __attribute__((ext_vector_type(4)));

// fast log1mexp for v < 0: log(1 - e^v). Rel err ~1e-6.
__device__ __forceinline__ float fast_log1mexp(float v) {
    if (v > -0.125f) {
        float e = v * (1.0f + v * (0.5f + v * (0.16666667f + v * 0.041666667f)));
        return __logf(-e);
    }
    return __logf(1.0f - __expf(v));
}

// w (fp32) -> wh (fp16)
__global__ __launch_bounds__(256) void cvt_kernel(const float* __restrict__ w,
                                                  _Float16* __restrict__ wh, int n) {
    int i = blockIdx.x * blockDim.x + threadIdx.x;
    int n4 = n >> 2;
    if (i < n4) {
        v4f v = reinterpret_cast<const v4f*>(w)[i];
        v4h o;
        o.x = (_Float16)v.x; o.y = (_Float16)v.y;
        o.z = (_Float16)v.z; o.w = (_Float16)v.w;
        reinterpret_cast<v4h*>(wh)[i] = o;
    }
    int base = n4 << 2;
    if (i < (n - base)) wh[base + i] = (_Float16)w[base + i];
}

// decode encoded-x entry p from fp16 weight table (4 MB, L2-resident)
__device__ __forceinline__ float decode_h(const _Float16* __restrict__ wh, int p) {
    int j = (p >> 1) - 1;
    float v = (float)wh[j < 0 ? 0 : j];
    float r = (p & 1) ? fast_log1mexp(v) : v;
    if (p < 2) r = (p == 0) ? NEG_INF : 0.0f;
    return r;
}

// Layer 0: product node fused with encode. 4 nodes/thread for MLP.
__global__ __launch_bounds__(256) void sum4_enc_kernel(const _Float16* __restrict__ wh,
                                                       const v4i* __restrict__ ptrs,
                                                       _Float16* __restrict__ y, int n, int h) {
    int t = blockIdx.x * blockDim.x + threadIdx.x;
    if (t >= h) return;
    #pragma unroll
    for (int k = 0; k < 4; k++) {
        int i = t + k * h;
        if (i >= n) break;
        v4i p = __builtin_nontemporal_load(ptrs + i);
        float s = (decode_h(wh, p.x) + decode_h(wh, p.y)) + (decode_h(wh, p.z) + decode_h(wh, p.w));
        __builtin_nontemporal_store((_Float16)s, y + i);
    }
}

// Product node: fp16 gather -> fp16 out, 4 nodes/thread.
__global__ __launch_bounds__(256) void sum4_h2h_kernel(const _Float16* __restrict__ x,
                                                       const v4i* __restrict__ ptrs,
                                                       _Float16* __restrict__ y, int n, int h) {
    int t = blockIdx.x * blockDim.x + threadIdx.x;
    if (t >= h) return;
    #pragma unroll
    for (int k = 0; k < 4; k++) {
        int i = t + k * h;
        if (i >= n) break;
        v4i p = __builtin_nontemporal_load(ptrs + i);
        float s = ((float)x[p.x] + (float)x[p.y]) + ((float)x[p.z] + (float)x[p.w]);
        __builtin_nontemporal_store((_Float16)s, y + i);
    }
}

__device__ __forceinline__ float lse4(float a, float b, float c, float d) {
    float m = fmaxf(fmaxf(a, b), fmaxf(c, d));
    if (m == NEG_INF) return NEG_INF;
    float s = __expf(a - m) + __expf(b - m) + __expf(c - m) + __expf(d - m) + 1e-15f;
    return __logf(s) + m;
}

// Layer 1 pass A: gather only ptrs in [0, half) — 4 MB L2-resident slice of x.
// Emit per-node partial max m and partial sum s = sum(exp(g - m)) (0 if m = -inf).
__global__ __launch_bounds__(256) void l1_passA_kernel(const _Float16* __restrict__ x,
                                                       const v4i* __restrict__ ptrs,
                                                       float* __restrict__ mA,
                                                       float* __restrict__ sA,
                                                       int n, int h, int half) {
    int t = blockIdx.x * blockDim.x + threadIdx.x;
    if (t >= h) return;
    #pragma unroll
    for (int k = 0; k < 4; k++) {
        int i = t + k * h;
        if (i >= n) break;
        v4i p = __builtin_nontemporal_load(ptrs + i);
        float a = (p.x < half) ? (float)x[p.x] : NEG_INF;
        float b = (p.y < half) ? (float)x[p.y] : NEG_INF;
        float c = (p.z < half) ? (float)x[p.z] : NEG_INF;
        float d = (p.w < half) ? (float)x[p.w] : NEG_INF;
        float m = fmaxf(fmaxf(a, b), fmaxf(c, d));
        float s = (m == NEG_INF) ? 0.0f
                : __expf(a - m) + __expf(b - m) + __expf(c - m) + __expf(d - m);
        __builtin_nontemporal_store(m, mA + i);
        __builtin_nontemporal_store(s, sA + i);
    }
}

// Layer 1 pass B: gather ptrs in [half, n0) (other 4 MB slice), merge with pass-A
// partials: m = max(mA,mB); s = sA*e^(mA-m) + sB*e^(mB-m) + eps; out = log(s)+m.
__global__ __launch_bounds__(256) void l1_passB_kernel(const _Float16* __restrict__ x,
                                                       const v4i* __restrict__ ptrs,
                                                       const float* __restrict__ mA,
                                                       const float* __restrict__ sA,
                                                       _Float16* __restrict__ y,
                                                       int n, int h, int half) {
    int t = blockIdx.x * blockDim.x + threadIdx.x;
    if (t >= h) return;
    #pragma unroll
    for (int k = 0; k < 4; k++) {
        int i = t + k * h;
        if (i >= n) break;
        v4i p = __builtin_nontemporal_load(ptrs + i);
        float a = (p.x >= half) ? (float)x[p.x] : NEG_INF;
        float b = (p.y >= half) ? (float)x[p.y] : NEG_INF;
        float c = (p.z >= half) ? (float)x[p.z] : NEG_INF;
        float d = (p.w >= half) ? (float)x[p.w] : NEG_INF;
        float mB = fmaxf(fmaxf(a, b), fmaxf(c, d));
        float sB = (mB == NEG_INF) ? 0.0f
                 : __expf(a - mB) + __expf(b - mB) + __expf(c - mB) + __expf(d - mB);
        float ma = __builtin_nontemporal_load(mA + i);
        float sa = __builtin_nontemporal_load(sA + i);
        float m = fmaxf(ma, mB);
        float out;
        if (m == NEG_INF) {
            out = NEG_INF;
        } else {
            // e^(-inf - m) = 0 handles empty/all-(-inf) partials
            float s = sa * __expf(ma - m) + sB * __expf(mB - m) + 1e-15f;
            out = __logf(s) + m;
        }
        __builtin_nontemporal_store((_Float16)out, y + i);
    }
}

// Final sum node: fp16 gather -> fp32 out, 4 nodes/thread.
__global__ __launch_bounds__(256) void logsum4_h2f_kernel(const _Float16* __restrict__ x,
                                                          const v4i* __restrict__ ptrs,
                                                          float* __restrict__ y, int n, int h) {
    int t = blockIdx.x * blockDim.x + threadIdx.x;
    if (t >= h) return;
    #pragma unroll
    for (int k = 0; k < 4; k++) {
        int i = t + k * h;
        if (i >= n) break;
        v4i p = __builtin_nontemporal_load(ptrs + i);
        float r = lse4((float)x[p.x], (float)x[p.y], (float)x[p.z], (float)x[p.w]);
        __builtin_nontemporal_store(r, y + i);
    }
}

extern "C" void kernel_launch(void* const* d_in, const int* in_sizes, int n_in,
                              void* d_out, int out_size, void* d_ws, size_t ws_size,
                              hipStream_t stream) {
    // d_in dict order: weights, ptrs0, csr0, n0, ptrs1, csr1, n1, ptrs2, csr2, n2, ptrs3, csr3, n3
    const float* w     = (const float*)d_in[0];
    const v4i*   ptrs0 = (const v4i*)d_in[1];
    const v4i*   ptrs1 = (const v4i*)d_in[4];
    const v4i*   ptrs2 = (const v4i*)d_in[7];
    const v4i*   ptrs3 = (const v4i*)d_in[10];

    const int n_vars = in_sizes[0];
    const int n0 = in_sizes[1] / 4;
    const int n1 = in_sizes[4] / 4;
    const int n2 = in_sizes[7] / 4;
    const int n3 = in_sizes[10] / 4;

    // workspace layout (256B-aligned)
    char* ws = (char*)d_ws;
    size_t off = 0;
    _Float16* wh = (_Float16*)(ws + off); off += ((size_t)n_vars * 2 + 255) & ~(size_t)255;
    _Float16* y0 = (_Float16*)(ws + off); off += ((size_t)n0 * 2 + 255) & ~(size_t)255;
    _Float16* y1 = (_Float16*)(ws + off); off += ((size_t)n1 * 2 + 255) & ~(size_t)255;
    _Float16* y2 = (_Float16*)(ws + off); off += ((size_t)n2 * 2 + 255) & ~(size_t)255;
    float*    mA = (float*)(ws + off);    off += ((size_t)n1 * 4 + 255) & ~(size_t)255;
    float*    sA = (float*)(ws + off);
    float* out = (float*)d_out;

    const int B = 256;
    int hc = (n_vars + 3) / 4;
    int h0 = (n0 + 3) / 4, h1 = (n1 + 3) / 4, h2 = (n2 + 3) / 4, h3 = (n3 + 3) / 4;
    int half0 = n0 / 2;   // 4 MB fp16 slice boundary of y0

    cvt_kernel        <<<(hc + B - 1) / B, B, 0, stream>>>(w, wh, n_vars);
    sum4_enc_kernel   <<<(h0 + B - 1) / B, B, 0, stream>>>(wh, ptrs0, y0, n0, h0);
    l1_passA_kernel   <<<(h1 + B - 1) / B, B, 0, stream>>>(y0, ptrs1, mA, sA, n1, h1, half0);
    l1_passB_kernel   <<<(h1 + B - 1) / B, B, 0, stream>>>(y0, ptrs1, mA, sA, y1, n1, h1, half0);
    sum4_h2h_kernel   <<<(h2 + B - 1) / B, B, 0, stream>>>(y1, ptrs2, y2, n2, h2);
    logsum4_h2f_kernel<<<(h3 + B - 1) / B, B, 0, stream>>>(y2, ptrs3, out, n3, h3);
}